// Round 11
// baseline (367.434 us; speedup 1.0000x reference)
//
#include <hip/hip_runtime.h>
#include <hip/hip_bf16.h>
#include <hip/hip_fp16.h>
#include <hip/hip_cooperative_groups.h>

namespace cg = cooperative_groups;

#define EPS 1e-9f
#define LN_EPS 1e-5f

typedef __attribute__((ext_vector_type(8))) short bf16x8;
typedef __attribute__((ext_vector_type(4))) float f32x4;

// ---------- helpers ----------
__device__ __forceinline__ float lo16(unsigned p) { return __uint_as_float(p << 16); }
__device__ __forceinline__ float hi16(unsigned p) { return __uint_as_float(p & 0xffff0000u); }
__device__ __forceinline__ unsigned f2b(float f) {
    unsigned u = __float_as_uint(f);
    return (u + 0x7fffu + ((u >> 16) & 1u)) >> 16;  // round-to-nearest-even
}
__device__ __forceinline__ int eidx(const int* ei, size_t i, int i64) {
    return i64 ? ei[2 * i] : ei[i];   // little-endian: low dword of int64
}
__device__ __forceinline__ float ldw(const float* fp, const __hip_bfloat16* hp, int i, int f32) {
    return f32 ? fp[i] : __bfloat162float(hp[i]);
}

// ---------- K1: merged prep (self-probing): [0,64) W->bf16 Wt; [64,64+zb) zero count(+ticket);
// rest x->bf16. Each block computes dtype flags itself; block 0 publishes for later kernels. ----------
__global__ void prep(const unsigned* __restrict__ xb, const float4* __restrict__ xf4,
                     uint2* __restrict__ xcvt2, const int* __restrict__ ei,
                     const unsigned* __restrict__ Wsb, const float* __restrict__ Wsf,
                     const unsigned* __restrict__ Wnb, const float* __restrict__ Wnf,
                     unsigned* __restrict__ wt, int4* __restrict__ count4,
                     int* __restrict__ flags, int* __restrict__ ticket,
                     int n4, int zb, int N4z) {
    __shared__ int sf[2];
    if (threadIdx.x < 64) {                          // wave 0: dtype probe
        int lane = threadIdx.x;
        unsigned d = xb[lane * 97];
        unsigned ex = (d >> 7) & 0xFFu;              // bf16-packed: low-half bf16 exponent field
        unsigned long long m1 = __ballot(ex >= 110u && ex <= 135u);
        int hi = ei[2 * lane + 1];                   // int64: odd dwords are all zero
        unsigned long long m2 = __ballot(hi == 0);
        if (lane == 0) {
            sf[0] = (__popcll(m1) > 32) ? 0 : 1;     // many bf16-exponent hits -> packed bf16
            sf[1] = (__popcll(m2) > 32) ? 1 : 0;
        }
    }
    __syncthreads();
    int f32 = sf[0];
    int b = blockIdx.x;
    if (b == 0 && threadIdx.x == 0) { flags[0] = sf[0]; flags[1] = sf[1]; }
    if (b < 64) {
        int tid = b * 256 + threadIdx.x;             // 16384 threads: f = tid>>7, k-pair = tid&127
        int f = tid >> 7, k2 = tid & 127;
        int k2l = k2 & 63;
        unsigned out;
        if (f32) {
            const float* W = (k2 < 64) ? Wsf : Wnf;
            float lo = W[(2 * k2l) * 128 + f], hi = W[(2 * k2l + 1) * 128 + f];
            out = f2b(lo) | (f2b(hi) << 16);
        } else {
            const unsigned* W = (k2 < 64) ? Wsb : Wnb;
            unsigned lo = W[(2 * k2l) * 64 + (f >> 1)];
            unsigned hi = W[(2 * k2l + 1) * 64 + (f >> 1)];
            unsigned a = (f & 1) ? (lo >> 16) : (lo & 0xffffu);
            unsigned b2 = (f & 1) ? (hi & 0xffff0000u) : (hi << 16);
            out = a | b2;
        }
        wt[tid] = out;
    } else if (b < 64 + zb) {
        int i = (b - 64) * 256 + threadIdx.x;        // uint4 index into count region
        if (i < N4z) count4[i] = make_int4(0, 0, 0, 0);
        if (b == 64 && threadIdx.x == 0) *ticket = 0;
    } else {
        if (!f32) return;                            // bf16 inputs: no copy needed
        int i = (b - 64 - zb) * 256 + threadIdx.x;
        if (i >= n4) return;
        float4 v = xf4[i];
        xcvt2[i] = make_uint2(f2b(v.x) | (f2b(v.y) << 16), f2b(v.z) | (f2b(v.w) << 16));
    }
}

// ---------- K2-cooperative: fused count + scan + scatter. Edge data held in registers
// across phases (no rank/tgt/weight global round-trips). 8 edges/thread. ----------
// PACK=1 (N<=65536): 4B record {src:16 | alpha:fp16:16}; else 8B {src, alpha:f32}.
template <int PACK>
__global__ __launch_bounds__(256) void edge_pipeline(
    const int* __restrict__ ei, int* __restrict__ count, int* __restrict__ offsets,
    int* __restrict__ bsum, int* __restrict__ bpre,
    const float* __restrict__ ewf, const __hip_bfloat16* __restrict__ ewh,
    unsigned* __restrict__ csr4, uint2* __restrict__ csr8,
    const int* __restrict__ flags, int E, int N, int scanB)
{
    __shared__ int wsum2[4];
    cg::grid_group grid = cg::this_grid();
    int f32 = flags[0], i64 = flags[1];
    int base = (blockIdx.x * 256 + threadIdx.x) * 8;
    int t[8], s_[8], r_[8];
    float wv[8];
    int have = 0;

    // ---- phase 1: load 8 edges into registers, atomic rank ----
    if (base < E) {
        have = E - base; if (have > 8) have = 8;
        if (have == 8) {
            if (i64 && !(E & 1)) {
                const int4* qt = (const int4*)(ei + 2 * (size_t)(E + base));
                int4 a = qt[0], b = qt[1], c = qt[2], d = qt[3];
                t[0]=a.x; t[1]=a.z; t[2]=b.x; t[3]=b.z; t[4]=c.x; t[5]=c.z; t[6]=d.x; t[7]=d.z;
                const int4* qs = (const int4*)(ei + 2 * (size_t)base);
                int4 e4 = qs[0], g4 = qs[1], h4 = qs[2], m4 = qs[3];
                s_[0]=e4.x; s_[1]=e4.z; s_[2]=g4.x; s_[3]=g4.z; s_[4]=h4.x; s_[5]=h4.z; s_[6]=m4.x; s_[7]=m4.z;
            } else if (!i64 && !(E & 3)) {
                const int4* qt = (const int4*)(ei + (size_t)E + base);
                int4 a = qt[0], b = qt[1];
                t[0]=a.x; t[1]=a.y; t[2]=a.z; t[3]=a.w; t[4]=b.x; t[5]=b.y; t[6]=b.z; t[7]=b.w;
                const int4* qs = (const int4*)(ei + base);
                int4 c4 = qs[0], d4 = qs[1];
                s_[0]=c4.x; s_[1]=c4.y; s_[2]=c4.z; s_[3]=c4.w; s_[4]=d4.x; s_[5]=d4.y; s_[6]=d4.z; s_[7]=d4.w;
            } else {
                #pragma unroll
                for (int k = 0; k < 8; ++k) {
                    t[k]  = eidx(ei, (size_t)E + base + k, i64);
                    s_[k] = eidx(ei, (size_t)base + k, i64);
                }
            }
            if (f32) {
                const float4* qw = (const float4*)(ewf + base);
                float4 wa = qw[0], wb = qw[1];
                wv[0]=wa.x; wv[1]=wa.y; wv[2]=wa.z; wv[3]=wa.w;
                wv[4]=wb.x; wv[5]=wb.y; wv[6]=wb.z; wv[7]=wb.w;
            } else {
                uint4 u = *(const uint4*)(ewh + base);   // 8 bf16, 16B aligned (base%8==0)
                wv[0]=lo16(u.x); wv[1]=hi16(u.x); wv[2]=lo16(u.y); wv[3]=hi16(u.y);
                wv[4]=lo16(u.z); wv[5]=hi16(u.z); wv[6]=lo16(u.w); wv[7]=hi16(u.w);
            }
        } else {
            #pragma unroll
            for (int k = 0; k < 8; ++k) if (k < have) {
                t[k]  = eidx(ei, (size_t)E + base + k, i64);
                s_[k] = eidx(ei, (size_t)base + k, i64);
                wv[k] = ldw(ewf, ewh, base + k, f32);
            }
        }
        #pragma unroll
        for (int k = 0; k < 8; ++k) if (k < have) r_[k] = atomicAdd(&count[t[k]], 1);
    }
    __threadfence();
    grid.sync();

    // ---- phase 2: local exclusive scan over counts (blocks < scanB; 4096 elems each) ----
    if (blockIdx.x < scanB) {
        int tid = threadIdx.x, lane = tid & 63, w = tid >> 6;
        int i0 = blockIdx.x * 4096 + tid * 16;
        int vv[16];
        if (i0 + 15 < N) {
            #pragma unroll
            for (int q = 0; q < 4; ++q) {
                int4 v = *(const int4*)(count + i0 + q * 4);
                vv[q*4+0] = v.x; vv[q*4+1] = v.y; vv[q*4+2] = v.z; vv[q*4+3] = v.w;
            }
        } else {
            #pragma unroll
            for (int q = 0; q < 16; ++q) vv[q] = (i0 + q < N) ? count[i0 + q] : 0;
        }
        int s = 0;
        #pragma unroll
        for (int q = 0; q < 16; ++q) s += vv[q];
        int incl = s;
        #pragma unroll
        for (int off = 1; off < 64; off <<= 1) {
            int tt = __shfl_up(incl, off);
            if (lane >= off) incl += tt;
        }
        if (lane == 63) wsum2[w] = incl;
        __syncthreads();
        int wpre = 0, tot = 0;
        #pragma unroll
        for (int j = 0; j < 4; ++j) { int sj = wsum2[j]; if (j < w) wpre += sj; tot += sj; }
        int run = wpre + incl - s;
        if (i0 + 15 < N) {
            #pragma unroll
            for (int q = 0; q < 4; ++q) {
                int4 o;
                o.x = run; run += vv[q*4+0];
                o.y = run; run += vv[q*4+1];
                o.z = run; run += vv[q*4+2];
                o.w = run; run += vv[q*4+3];
                *(int4*)(offsets + i0 + q * 4) = o;
            }
        } else {
            #pragma unroll
            for (int q = 0; q < 16; ++q) { if (i0 + q < N) offsets[i0 + q] = run; run += vv[q]; }
        }
        if (tid == 0) bsum[blockIdx.x] = tot;
    }
    __threadfence();
    grid.sync();

    // ---- phase 2.5: block-prefix table ----
    if (blockIdx.x == 0 && threadIdx.x == 0) {
        int run = 0;
        for (int j = 0; j < scanB; ++j) { bpre[j] = run; run += bsum[j]; }
        bpre[scanB] = run;
        offsets[N] = (N & 4095) ? (run - bpre[scanB - 1]) : 0;
    }
    __threadfence();
    grid.sync();

    // ---- phase 3: scatter from registers ----
    if (base < E) {
        #pragma unroll
        for (int k = 0; k < 8; ++k) if (k < have) {
            int tk = t[k];
            int pos = offsets[tk] + bpre[tk >> 12] + r_[k];
            float al = expf(wv[k]);
            if (PACK) csr4[pos] = (unsigned)s_[k] | ((unsigned)__half_as_ushort(__float2half(al)) << 16);
            else      csr8[pos] = make_uint2((unsigned)s_[k], __float_as_uint(al));
        }
    }
}

// ================= fallback path (separate dispatches), proven in round 10 =================
__global__ void edge_count(const int* __restrict__ ei, int* __restrict__ count,
                           int* __restrict__ rank, const int* __restrict__ flags, int E) {
    int e0 = (blockIdx.x * 256 + threadIdx.x) * 4;
    if (e0 >= E) return;
    int i64 = flags[1];
    if (e0 + 4 <= E) {
        int t0, t1, t2, t3;
        if (i64 && !(E & 1)) {
            const int4* q = (const int4*)(ei + 2 * (size_t)(E + e0));
            int4 a = q[0], b = q[1];
            t0 = a.x; t1 = a.z; t2 = b.x; t3 = b.z;
        } else if (!i64 && !(E & 3)) {
            int4 a = *(const int4*)(ei + (size_t)E + e0);
            t0 = a.x; t1 = a.y; t2 = a.z; t3 = a.w;
        } else {
            t0 = eidx(ei, (size_t)E + e0 + 0, i64); t1 = eidx(ei, (size_t)E + e0 + 1, i64);
            t2 = eidx(ei, (size_t)E + e0 + 2, i64); t3 = eidx(ei, (size_t)E + e0 + 3, i64);
        }
        int r0 = atomicAdd(&count[t0], 1), r1 = atomicAdd(&count[t1], 1),
            r2 = atomicAdd(&count[t2], 1), r3 = atomicAdd(&count[t3], 1);
        *(int4*)(rank + e0) = make_int4(r0, r1, r2, r3);
    } else {
        for (int j = 0; j < 4 && e0 + j < E; ++j) {
            int t = eidx(ei, (size_t)E + e0 + j, i64);
            rank[e0 + j] = atomicAdd(&count[t], 1);
        }
    }
}

__global__ void scan_blocks(const int* __restrict__ count, int* __restrict__ offsets,
                            int* __restrict__ bsum, int* __restrict__ bpre,
                            int* __restrict__ ticket, int N, int B) {
    __shared__ int wsum[16];
    int tid = threadIdx.x, lane = tid & 63, w = tid >> 6;
    int i0 = blockIdx.x * 4096 + tid * 4;
    int4 v;
    if (i0 + 3 < N) v = *(const int4*)(count + i0);
    else {
        v.x = (i0     < N) ? count[i0]     : 0;
        v.y = (i0 + 1 < N) ? count[i0 + 1] : 0;
        v.z = (i0 + 2 < N) ? count[i0 + 2] : 0;
        v.w = (i0 + 3 < N) ? count[i0 + 3] : 0;
    }
    int s = v.x + v.y + v.z + v.w;
    int incl = s;
    #pragma unroll
    for (int off = 1; off < 64; off <<= 1) {
        int t = __shfl_up(incl, off);
        if (lane >= off) incl += t;
    }
    if (lane == 63) wsum[w] = incl;
    __syncthreads();
    int wpre = 0, tot = 0;
    #pragma unroll
    for (int j = 0; j < 16; ++j) { int sj = wsum[j]; if (j < w) wpre += sj; tot += sj; }
    int o0 = wpre + incl - s;
    int o1 = o0 + v.x, o2 = o1 + v.y, o3 = o2 + v.z;
    if (i0 + 3 < N) {
        *(int4*)(offsets + i0) = make_int4(o0, o1, o2, o3);
    } else {
        if (i0     < N) offsets[i0]     = o0;
        if (i0 + 1 < N) offsets[i0 + 1] = o1;
        if (i0 + 2 < N) offsets[i0 + 2] = o2;
    }
    if (tid == 0) {
        bsum[blockIdx.x] = tot;
        __threadfence();
        int t = atomicAdd(ticket, 1);
        if (t == B - 1) {
            int run = 0;
            for (int j = 0; j < B; ++j) {
                int vj = atomicAdd(&bsum[j], 0);
                bpre[j] = run; run += vj;
            }
            bpre[B] = run;
            offsets[N] = (N & 4095) ? (run - bpre[B - 1]) : 0;
        }
    }
}

template <int PACK>
__global__ void edge_scatter(const int* __restrict__ ei, const int* __restrict__ rank,
                             const float* __restrict__ ewf, const __hip_bfloat16* __restrict__ ewh,
                             const int* __restrict__ offsets, const int* __restrict__ bpre,
                             unsigned* __restrict__ csr4, uint2* __restrict__ csr8,
                             const int* __restrict__ flags, int E) {
    int e0 = (blockIdx.x * 256 + threadIdx.x) * 4;
    if (e0 >= E) return;
    int f32 = flags[0], i64 = flags[1];
    if (e0 + 4 <= E) {
        int4 r = *(const int4*)(rank + e0);
        int t0, t1, t2, t3, s0, s1, s2, s3;
        if (i64) {
            const int4* q = (const int4*)(ei + 2 * (size_t)e0);
            int4 a = q[0], b = q[1];
            s0 = a.x; s1 = a.z; s2 = b.x; s3 = b.z;
        } else if (!(e0 & 3)) {
            int4 a = *(const int4*)(ei + e0);
            s0 = a.x; s1 = a.y; s2 = a.z; s3 = a.w;
        } else {
            s0 = ei[e0]; s1 = ei[e0 + 1]; s2 = ei[e0 + 2]; s3 = ei[e0 + 3];
        }
        if (i64 && !(E & 1)) {
            const int4* q = (const int4*)(ei + 2 * (size_t)(E + e0));
            int4 a = q[0], b = q[1];
            t0 = a.x; t1 = a.z; t2 = b.x; t3 = b.z;
        } else if (!i64 && !(E & 3)) {
            int4 a = *(const int4*)(ei + (size_t)E + e0);
            t0 = a.x; t1 = a.y; t2 = a.z; t3 = a.w;
        } else {
            t0 = eidx(ei, (size_t)E + e0 + 0, i64); t1 = eidx(ei, (size_t)E + e0 + 1, i64);
            t2 = eidx(ei, (size_t)E + e0 + 2, i64); t3 = eidx(ei, (size_t)E + e0 + 3, i64);
        }
        float w0 = ldw(ewf, ewh, e0 + 0, f32), w1 = ldw(ewf, ewh, e0 + 1, f32),
              w2 = ldw(ewf, ewh, e0 + 2, f32), w3 = ldw(ewf, ewh, e0 + 3, f32);
        int o0 = offsets[t0] + bpre[t0 >> 12] + r.x,
            o1 = offsets[t1] + bpre[t1 >> 12] + r.y,
            o2 = offsets[t2] + bpre[t2 >> 12] + r.z,
            o3 = offsets[t3] + bpre[t3 >> 12] + r.w;
        float a0 = expf(w0), a1 = expf(w1), a2 = expf(w2), a3 = expf(w3);
        if (PACK) {
            csr4[o0] = (unsigned)s0 | ((unsigned)__half_as_ushort(__float2half(a0)) << 16);
            csr4[o1] = (unsigned)s1 | ((unsigned)__half_as_ushort(__float2half(a1)) << 16);
            csr4[o2] = (unsigned)s2 | ((unsigned)__half_as_ushort(__float2half(a2)) << 16);
            csr4[o3] = (unsigned)s3 | ((unsigned)__half_as_ushort(__float2half(a3)) << 16);
        } else {
            csr8[o0] = make_uint2((unsigned)s0, __float_as_uint(a0));
            csr8[o1] = make_uint2((unsigned)s1, __float_as_uint(a1));
            csr8[o2] = make_uint2((unsigned)s2, __float_as_uint(a2));
            csr8[o3] = make_uint2((unsigned)s3, __float_as_uint(a3));
        }
    } else {
        for (int j = 0; j < 4 && e0 + j < E; ++j) {
            int e = e0 + j;
            int t = eidx(ei, (size_t)E + e, i64);
            int s = eidx(ei, e, i64);
            float al = expf(ldw(ewf, ewh, e, f32));
            int pos = offsets[t] + bpre[t >> 12] + rank[e];
            if (PACK) csr4[pos] = (unsigned)s | ((unsigned)__half_as_ushort(__float2half(al)) << 16);
            else      csr8[pos] = make_uint2((unsigned)s, __float_as_uint(al));
        }
    }
}
// ================= end fallback path =================

// ---------- CSR record decode ----------
template <int PACK>
__device__ __forceinline__ void dec_edge(const unsigned* __restrict__ c4,
                                         const uint2* __restrict__ c8, int j,
                                         unsigned& s, float& al) {
    if (PACK) {
        unsigned r = c4[j];
        s = r & 0xffffu;
        al = __half2float(__ushort_as_half((unsigned short)(r >> 16)));
    } else {
        uint2 e = c8[j];
        s = e.x;
        al = __uint_as_float(e.y);
    }
}

// ---------- K5: TWO nodes per wave (32 lanes each); always-8-deep predicated gather ----------
template <int PACK>
__global__ void aggregate(const unsigned* __restrict__ xb, const unsigned* __restrict__ xcvt,
                          const int* __restrict__ offsets, const int* __restrict__ bpre,
                          const unsigned* __restrict__ csr4, const uint2* __restrict__ csr8,
                          uint2* __restrict__ aggb2, const int* __restrict__ flags, int N) {
    int wid = blockIdx.x * 4 + (threadIdx.x >> 6);
    int half = (threadIdx.x >> 5) & 1;
    int node = wid * 2 + half;
    if (node >= N) return;
    int lane32 = threadIdx.x & 31;
    const uint2* xs2 = (const uint2*)(flags[0] ? xcvt : xb);  // bf16 rows, 32 uint2 each
    float a0 = 0.f, a1 = 0.f, a2 = 0.f, a3 = 0.f;
    int beg = offsets[node] + bpre[node >> 12];
    int end = offsets[node + 1] + bpre[(node + 1) >> 12];
    for (int j = beg; j < end; j += 8) {
        int last = end - 1;
        int j0 = j,     i0 = (j0 < end) ? j0 : last;
        int j1 = j + 1, i1 = (j1 < end) ? j1 : last;
        int j2 = j + 2, i2 = (j2 < end) ? j2 : last;
        int j3 = j + 3, i3 = (j3 < end) ? j3 : last;
        int j4 = j + 4, i4 = (j4 < end) ? j4 : last;
        int j5 = j + 5, i5 = (j5 < end) ? j5 : last;
        int j6 = j + 6, i6 = (j6 < end) ? j6 : last;
        int j7 = j + 7, i7 = (j7 < end) ? j7 : last;
        unsigned s0, s1, s2, s3, s4, s5, s6, s7;
        float l0, l1, l2, l3, l4, l5, l6, l7;
        dec_edge<PACK>(csr4, csr8, i0, s0, l0); dec_edge<PACK>(csr4, csr8, i1, s1, l1);
        dec_edge<PACK>(csr4, csr8, i2, s2, l2); dec_edge<PACK>(csr4, csr8, i3, s3, l3);
        dec_edge<PACK>(csr4, csr8, i4, s4, l4); dec_edge<PACK>(csr4, csr8, i5, s5, l5);
        dec_edge<PACK>(csr4, csr8, i6, s6, l6); dec_edge<PACK>(csr4, csr8, i7, s7, l7);
        uint2 p0 = xs2[s0 * 32 + lane32], p1 = xs2[s1 * 32 + lane32],
              p2 = xs2[s2 * 32 + lane32], p3 = xs2[s3 * 32 + lane32],
              p4 = xs2[s4 * 32 + lane32], p5 = xs2[s5 * 32 + lane32],
              p6 = xs2[s6 * 32 + lane32], p7 = xs2[s7 * 32 + lane32];
        l1 = (j1 < end) ? l1 : 0.f; l2 = (j2 < end) ? l2 : 0.f;
        l3 = (j3 < end) ? l3 : 0.f; l4 = (j4 < end) ? l4 : 0.f;
        l5 = (j5 < end) ? l5 : 0.f; l6 = (j6 < end) ? l6 : 0.f;
        l7 = (j7 < end) ? l7 : 0.f;
        a0 += l0 * lo16(p0.x); a1 += l0 * hi16(p0.x); a2 += l0 * lo16(p0.y); a3 += l0 * hi16(p0.y);
        a0 += l1 * lo16(p1.x); a1 += l1 * hi16(p1.x); a2 += l1 * lo16(p1.y); a3 += l1 * hi16(p1.y);
        a0 += l2 * lo16(p2.x); a1 += l2 * hi16(p2.x); a2 += l2 * lo16(p2.y); a3 += l2 * hi16(p2.y);
        a0 += l3 * lo16(p3.x); a1 += l3 * hi16(p3.x); a2 += l3 * lo16(p3.y); a3 += l3 * hi16(p3.y);
        a0 += l4 * lo16(p4.x); a1 += l4 * hi16(p4.x); a2 += l4 * lo16(p4.y); a3 += l4 * hi16(p4.y);
        a0 += l5 * lo16(p5.x); a1 += l5 * hi16(p5.x); a2 += l5 * lo16(p5.y); a3 += l5 * hi16(p5.y);
        a0 += l6 * lo16(p6.x); a1 += l6 * hi16(p6.x); a2 += l6 * lo16(p6.y); a3 += l6 * hi16(p6.y);
        a0 += l7 * lo16(p7.x); a1 += l7 * hi16(p7.x); a2 += l7 * lo16(p7.y); a3 += l7 * hi16(p7.y);
    }
    float ss = a0 * a0 + a1 * a1 + a2 * a2 + a3 * a3;
    #pragma unroll
    for (int m = 16; m >= 1; m >>= 1) ss += __shfl_xor(ss, m);   // reduce within 32-lane half
    float inv = 1.f / (sqrtf(ss) + EPS);
    aggb2[node * 32 + lane32] = make_uint2(f2b(a0 * inv) | (f2b(a1 * inv) << 16),
                                           f2b(a2 * inv) | (f2b(a3 * inv) << 16));
}

// ---------- K6: MFMA fused: C = 0.5*([x|agg] @ [Ws;Wn] + bs + bn) -> proj-norm -> LN ----------
// 64 nodes/block, 128 threads (2 waves), 32 KB LDS; each wave owns 32 nodes as TWO
// 16-row A-subtiles -> every loaded B fragment feeds 2 MFMAs (halves Wt L2 traffic/node).
__global__ __launch_bounds__(128) void fused_mfma(
    const unsigned* __restrict__ xb, const unsigned* __restrict__ xcvt,
    const unsigned* __restrict__ aggb, const uint4* __restrict__ wt4,
    const float* __restrict__ bsf, const __hip_bfloat16* __restrict__ bsh,
    const float* __restrict__ bnf, const __hip_bfloat16* __restrict__ bnh,
    const float* __restrict__ gf, const __hip_bfloat16* __restrict__ gh,
    const float* __restrict__ tf, const __hip_bfloat16* __restrict__ th,
    float* __restrict__ outf, unsigned* __restrict__ outb,
    const int* __restrict__ flags, int N)
{
    __shared__ uint4 sA[2048];                   // 64 rows x 32 chunks of 16B = 32 KB
    int f32 = flags[0];
    const uint4* xs4 = (const uint4*)(f32 ? xcvt : xb);
    const uint4* ag4 = (const uint4*)aggb;
    int tid = threadIdx.x;
    int node0 = blockIdx.x * 64;

    #pragma unroll
    for (int i = 0; i < 16; ++i) {
        int ci = i * 128 + tid;
        int r = ci >> 5, c = ci & 31;
        int node = node0 + r;
        uint4 v = make_uint4(0, 0, 0, 0);
        if (node < N) v = (c < 16) ? xs4[node * 16 + c] : ag4[node * 16 + (c - 16)];
        sA[r * 32 + (c ^ (r & 15))] = v;
    }
    __syncthreads();

    int lane = tid & 63, w = tid >> 6, g = lane >> 4, c16 = lane & 15;
    int rloc0 = w * 32 + c16;
    int rloc1 = rloc0 + 16;

    f32x4 acc0[8], acc1[8];
    #pragma unroll
    for (int t = 0; t < 8; ++t) {
        acc0[t] = (f32x4){0.f, 0.f, 0.f, 0.f};
        acc1[t] = (f32x4){0.f, 0.f, 0.f, 0.f};
    }

    #pragma unroll
    for (int kk = 0; kk < 8; ++kk) {             // K = 256 in steps of 32
        int cs = (kk * 4 + g) ^ c16;
        bf16x8 a0 = __builtin_bit_cast(bf16x8, sA[rloc0 * 32 + cs]);
        bf16x8 a1 = __builtin_bit_cast(bf16x8, sA[rloc1 * 32 + cs]);
        #pragma unroll
        for (int t = 0; t < 8; ++t) {            // 8 feature tiles of 16; B reused 2x
            uint4 bv = wt4[(t * 16 + c16) * 32 + kk * 4 + g];
            bf16x8 b = __builtin_bit_cast(bf16x8, bv);
            acc0[t] = __builtin_amdgcn_mfma_f32_16x16x32_bf16(a0, b, acc0[t], 0, 0, 0);
            acc1[t] = __builtin_amdgcn_mfma_f32_16x16x32_bf16(a1, b, acc1[t], 0, 0, 0);
        }
    }

    float bsum[8], gam[8], bet[8];
    #pragma unroll
    for (int t = 0; t < 8; ++t) {
        int f = t * 16 + c16;
        bsum[t] = ldw(bsf, bsh, f, f32) + ldw(bnf, bnh, f, f32);
        gam[t]  = ldw(gf, gh, f, f32);
        bet[t]  = ldw(tf, th, f, f32);
    }

    auto epilogue = [&](f32x4* acc, int rowbase) {
        #pragma unroll
        for (int reg = 0; reg < 4; ++reg) {
            int node = node0 + rowbase + g * 4 + reg;
            float cv[8], s1 = 0.f, s2 = 0.f;
            #pragma unroll
            for (int t = 0; t < 8; ++t) {
                float c_ = 0.5f * (acc[t][reg] + bsum[t]);
                cv[t] = c_; s1 += c_; s2 += c_ * c_;
            }
            #pragma unroll
            for (int m = 1; m < 16; m <<= 1) { s1 += __shfl_xor(s1, m); s2 += __shfl_xor(s2, m); }
            float inv  = 1.f / (sqrtf(s2) + EPS);
            float mean = s1 * inv * (1.f / 128.f);
            float var  = s2 * inv * inv * (1.f / 128.f) - mean * mean;
            float rstd = 1.f / sqrtf(var + LN_EPS);
            if (f32) {
                if (node < N) {
                    #pragma unroll
                    for (int t = 0; t < 8; ++t) {
                        float o = (cv[t] * inv - mean) * rstd * gam[t] + bet[t];
                        outf[(size_t)node * 128 + t * 16 + c16] = o;
                    }
                }
            } else {
                #pragma unroll
                for (int t = 0; t < 8; ++t) {
                    float o = (cv[t] * inv - mean) * rstd * gam[t] + bet[t];
                    float po = __shfl_xor(o, 1);
                    if (!(c16 & 1) && node < N)
                        outb[node * 64 + t * 8 + (c16 >> 1)] = f2b(o) | (f2b(po) << 16);
                }
            }
        }
    };
    epilogue(acc0, w * 32);
    epilogue(acc1, w * 32 + 16);
}

static inline size_t rup16(size_t x) { return (x + 15) & ~(size_t)15; }

extern "C" void kernel_launch(void* const* d_in, const int* in_sizes, int n_in,
                              void* d_out, int out_size, void* d_ws, size_t ws_size,
                              hipStream_t stream) {
    int N = in_sizes[0] / 128;
    int E = in_sizes[1] / 2;
    const int* ei = (const int*)d_in[1];

    char* p = (char*)d_ws;
    int* flags = (int*)p;              p += 16;
    int* ticket = (int*)p;             p += 16;
    int* count = (int*)p;              p += rup16((size_t)N * 4);
    int* offsets = (int*)p;            p += rup16((size_t)(N + 4) * 4);
    int* bsum = (int*)p;               p += 256;                       // up to 64 block sums
    int* bpre = (int*)p;               p += 512;                       // block-prefix table [B+1]
    int* rank = (int*)p;               p += rup16((size_t)E * 4);      // fallback path only
    unsigned* csr4 = (unsigned*)p;                                     // aliases csr8 region
    uint2* csr8 = (uint2*)p;           p += rup16((size_t)E * 8);
    unsigned* wt = (unsigned*)p;       p += 128 * 128 * 4;             // 64 KB bf16 Wt[128][256]
    unsigned* xcvt = (unsigned*)p;     p += rup16((size_t)N * 64 * 4); // 12.8 MB bf16 x copy
    unsigned* aggb = (unsigned*)p;     // N*64 u32 = 12.8 MB bf16 agg

    int eb4 = (E + 1023) / 1024;
    int nb2 = (N + 7) / 8;                       // aggregate: 8 nodes/block (2 per wave)
    int nbf = (N + 63) / 64;                     // fused_mfma: 64 nodes/block
    int ncv = (N * 32 + 255) / 256;
    int scanB = (N + 4095) / 4096;
    int N4z = (int)(rup16((size_t)N * 4) / 16);
    int zb = (N4z + 255) / 256;
    int pack = (N <= 65536);

    prep<<<64 + zb + ncv, 256, 0, stream>>>((const unsigned*)d_in[0], (const float4*)d_in[0],
                                            (uint2*)xcvt, ei,
                                            (const unsigned*)d_in[3], (const float*)d_in[3],
                                            (const unsigned*)d_in[5], (const float*)d_in[5],
                                            wt, (int4*)count, flags, ticket, N * 32, zb, N4z);

    // ---- fused cooperative edge pipeline (count+scan+scatter); fallback to 3 kernels ----
    const float* ewf_ = (const float*)d_in[2];
    const __hip_bfloat16* ewh_ = (const __hip_bfloat16*)d_in[2];
    int ep_blocks = (E + 2047) / 2048;
    if (ep_blocks < scanB) ep_blocks = scanB;
    void* args[] = { (void*)&ei, (void*)&count, (void*)&offsets, (void*)&bsum, (void*)&bpre,
                     (void*)&ewf_, (void*)&ewh_, (void*)&csr4, (void*)&csr8, (void*)&flags,
                     (void*)&E, (void*)&N, (void*)&scanB };
    hipError_t cerr = hipLaunchCooperativeKernel(
        pack ? (const void*)edge_pipeline<1> : (const void*)edge_pipeline<0>,
        dim3(ep_blocks), dim3(256), args, 0, stream);
    if (cerr != hipSuccess) {
        edge_count<<<eb4, 256, 0, stream>>>(ei, count, rank, flags, E);
        scan_blocks<<<scanB, 1024, 0, stream>>>(count, offsets, bsum, bpre, ticket, N, scanB);
        if (pack)
            edge_scatter<1><<<eb4, 256, 0, stream>>>(ei, rank, ewf_, ewh_,
                                                     offsets, bpre, csr4, csr8, flags, E);
        else
            edge_scatter<0><<<eb4, 256, 0, stream>>>(ei, rank, ewf_, ewh_,
                                                     offsets, bpre, csr4, csr8, flags, E);
    }

    if (pack)
        aggregate<1><<<nb2, 256, 0, stream>>>((const unsigned*)d_in[0], xcvt,
                                              offsets, bpre, csr4, csr8, (uint2*)aggb, flags, N);
    else
        aggregate<0><<<nb2, 256, 0, stream>>>((const unsigned*)d_in[0], xcvt,
                                              offsets, bpre, csr4, csr8, (uint2*)aggb, flags, N);
    fused_mfma<<<nbf, 128, 0, stream>>>((const unsigned*)d_in[0], xcvt, aggb, (const uint4*)wt,
                                        (const float*)d_in[4], (const __hip_bfloat16*)d_in[4],
                                        (const float*)d_in[6], (const __hip_bfloat16*)d_in[6],
                                        (const float*)d_in[7], (const __hip_bfloat16*)d_in[7],
                                        (const float*)d_in[8], (const __hip_bfloat16*)d_in[8],
                                        (float*)d_out, (unsigned*)d_out, flags, N);
}

// Round 12
// 195.102 us; speedup vs baseline: 1.8833x; 1.8833x over previous
//
#include <hip/hip_runtime.h>
#include <hip/hip_bf16.h>
#include <hip/hip_fp16.h>

#define EPS 1e-9f
#define LN_EPS 1e-5f

typedef __attribute__((ext_vector_type(8))) short bf16x8;
typedef __attribute__((ext_vector_type(4))) float f32x4;

// ---------- helpers ----------
__device__ __forceinline__ float lo16(unsigned p) { return __uint_as_float(p << 16); }
__device__ __forceinline__ float hi16(unsigned p) { return __uint_as_float(p & 0xffff0000u); }
__device__ __forceinline__ unsigned f2b(float f) {
    unsigned u = __float_as_uint(f);
    return (u + 0x7fffu + ((u >> 16) & 1u)) >> 16;  // round-to-nearest-even
}
__device__ __forceinline__ int eidx(const int* ei, size_t i, int i64) {
    return i64 ? ei[2 * i] : ei[i];   // little-endian: low dword of int64
}
__device__ __forceinline__ float ldw(const float* fp, const __hip_bfloat16* hp, int i, int f32) {
    return f32 ? fp[i] : __bfloat162float(hp[i]);
}

// ---------- K1: merged prep (self-probing): [0,64) W->bf16 Wt; [64,64+zb) zero count(+ticket);
// rest x->bf16. Each block computes dtype flags itself; block 0 publishes for later kernels. ----------
__global__ void prep(const unsigned* __restrict__ xb, const float4* __restrict__ xf4,
                     uint2* __restrict__ xcvt2, const int* __restrict__ ei,
                     const unsigned* __restrict__ Wsb, const float* __restrict__ Wsf,
                     const unsigned* __restrict__ Wnb, const float* __restrict__ Wnf,
                     unsigned* __restrict__ wt, int4* __restrict__ count4,
                     int* __restrict__ flags, int* __restrict__ ticket,
                     int n4, int zb, int N4z) {
    __shared__ int sf[2];
    if (threadIdx.x < 64) {                          // wave 0: dtype probe
        int lane = threadIdx.x;
        unsigned d = xb[lane * 97];
        unsigned ex = (d >> 7) & 0xFFu;              // bf16-packed: low-half bf16 exponent field
        unsigned long long m1 = __ballot(ex >= 110u && ex <= 135u);
        int hi = ei[2 * lane + 1];                   // int64: odd dwords are all zero
        unsigned long long m2 = __ballot(hi == 0);
        if (lane == 0) {
            sf[0] = (__popcll(m1) > 32) ? 0 : 1;     // many bf16-exponent hits -> packed bf16
            sf[1] = (__popcll(m2) > 32) ? 1 : 0;
        }
    }
    __syncthreads();
    int f32 = sf[0];
    int b = blockIdx.x;
    if (b == 0 && threadIdx.x == 0) { flags[0] = sf[0]; flags[1] = sf[1]; }
    if (b < 64) {
        int tid = b * 256 + threadIdx.x;             // 16384 threads: f = tid>>7, k-pair = tid&127
        int f = tid >> 7, k2 = tid & 127;
        int k2l = k2 & 63;
        unsigned out;
        if (f32) {
            const float* W = (k2 < 64) ? Wsf : Wnf;
            float lo = W[(2 * k2l) * 128 + f], hi = W[(2 * k2l + 1) * 128 + f];
            out = f2b(lo) | (f2b(hi) << 16);
        } else {
            const unsigned* W = (k2 < 64) ? Wsb : Wnb;
            unsigned lo = W[(2 * k2l) * 64 + (f >> 1)];
            unsigned hi = W[(2 * k2l + 1) * 64 + (f >> 1)];
            unsigned a = (f & 1) ? (lo >> 16) : (lo & 0xffffu);
            unsigned b2 = (f & 1) ? (hi & 0xffff0000u) : (hi << 16);
            out = a | b2;
        }
        wt[tid] = out;
    } else if (b < 64 + zb) {
        int i = (b - 64) * 256 + threadIdx.x;        // uint4 index into count region
        if (i < N4z) count4[i] = make_int4(0, 0, 0, 0);
        if (b == 64 && threadIdx.x == 0) *ticket = 0;
    } else {
        if (!f32) return;                            // bf16 inputs: no copy needed
        int i = (b - 64 - zb) * 256 + threadIdx.x;
        if (i >= n4) return;
        float4 v = xf4[i];
        xcvt2[i] = make_uint2(f2b(v.x) | (f2b(v.y) << 16), f2b(v.z) | (f2b(v.w) << 16));
    }
}

// ---------- K2: per-target degree count + arrival rank (4 edges/thread) ----------
__global__ void edge_count(const int* __restrict__ ei, int* __restrict__ count,
                           int* __restrict__ rank, const int* __restrict__ flags, int E) {
    int e0 = (blockIdx.x * 256 + threadIdx.x) * 4;
    if (e0 >= E) return;
    int i64 = flags[1];
    if (e0 + 4 <= E) {
        int t0, t1, t2, t3;
        if (i64 && !(E & 1)) {                       // 16B-aligned int64 target loads
            const int4* q = (const int4*)(ei + 2 * (size_t)(E + e0));
            int4 a = q[0], b = q[1];
            t0 = a.x; t1 = a.z; t2 = b.x; t3 = b.z;
        } else if (!i64 && !(E & 3)) {
            int4 a = *(const int4*)(ei + (size_t)E + e0);
            t0 = a.x; t1 = a.y; t2 = a.z; t3 = a.w;
        } else {
            t0 = eidx(ei, (size_t)E + e0 + 0, i64); t1 = eidx(ei, (size_t)E + e0 + 1, i64);
            t2 = eidx(ei, (size_t)E + e0 + 2, i64); t3 = eidx(ei, (size_t)E + e0 + 3, i64);
        }
        int r0 = atomicAdd(&count[t0], 1), r1 = atomicAdd(&count[t1], 1),
            r2 = atomicAdd(&count[t2], 1), r3 = atomicAdd(&count[t3], 1);
        *(int4*)(rank + e0) = make_int4(r0, r1, r2, r3);
    } else {
        for (int j = 0; j < 4 && e0 + j < E; ++j) {
            int t = eidx(ei, (size_t)E + e0 + j, i64);
            rank[e0 + j] = atomicAdd(&count[t], 1);
        }
    }
}

// ---------- K3: multi-block local exclusive scan; last-arriving block builds block-prefix
// table bpre[0..B] and offsets[N]. Readers use global_off(i) = offsets[i] + bpre[i>>12]. ----------
__global__ void scan_blocks(const int* __restrict__ count, int* __restrict__ offsets,
                            int* __restrict__ bsum, int* __restrict__ bpre,
                            int* __restrict__ ticket, int N, int B) {
    __shared__ int wsum[16];
    int tid = threadIdx.x, lane = tid & 63, w = tid >> 6;
    int i0 = blockIdx.x * 4096 + tid * 4;
    int4 v;
    if (i0 + 3 < N) v = *(const int4*)(count + i0);
    else {
        v.x = (i0     < N) ? count[i0]     : 0;
        v.y = (i0 + 1 < N) ? count[i0 + 1] : 0;
        v.z = (i0 + 2 < N) ? count[i0 + 2] : 0;
        v.w = (i0 + 3 < N) ? count[i0 + 3] : 0;
    }
    int s = v.x + v.y + v.z + v.w;
    int incl = s;
    #pragma unroll
    for (int off = 1; off < 64; off <<= 1) {
        int t = __shfl_up(incl, off);
        if (lane >= off) incl += t;
    }
    if (lane == 63) wsum[w] = incl;
    __syncthreads();
    int wpre = 0, tot = 0;
    #pragma unroll
    for (int j = 0; j < 16; ++j) { int sj = wsum[j]; if (j < w) wpre += sj; tot += sj; }
    int o0 = wpre + incl - s;
    int o1 = o0 + v.x, o2 = o1 + v.y, o3 = o2 + v.z;
    if (i0 + 3 < N) {
        *(int4*)(offsets + i0) = make_int4(o0, o1, o2, o3);
    } else {
        if (i0     < N) offsets[i0]     = o0;
        if (i0 + 1 < N) offsets[i0 + 1] = o1;
        if (i0 + 2 < N) offsets[i0 + 2] = o2;
    }
    if (tid == 0) {
        bsum[blockIdx.x] = tot;
        __threadfence();                             // make bsum visible device-wide
        int t = atomicAdd(ticket, 1);
        if (t == B - 1) {                            // last block: all bsum written
            int run = 0;
            for (int j = 0; j < B; ++j) {
                int vj = atomicAdd(&bsum[j], 0);     // device-scope read
                bpre[j] = run; run += vj;
            }
            bpre[B] = run;
            offsets[N] = (N & 4095) ? (run - bpre[B - 1]) : 0;  // local prefix at N
        }
    }
}

// ---------- K4: atomic-free scatter: pos = offsets[t] + bpre[t>>12] + rank[e] (4 edges/thread) ----------
// Targets recomputed from L2-hot ei (tgt32 array eliminated).
// PACK=1 (N<=65536): 4B record {src:16 | alpha:fp16:16}; else 8B {src, alpha:f32}.
template <int PACK>
__global__ void edge_scatter(const int* __restrict__ ei, const int* __restrict__ rank,
                             const float* __restrict__ ewf, const __hip_bfloat16* __restrict__ ewh,
                             const int* __restrict__ offsets, const int* __restrict__ bpre,
                             unsigned* __restrict__ csr4, uint2* __restrict__ csr8,
                             const int* __restrict__ flags, int E) {
    int e0 = (blockIdx.x * 256 + threadIdx.x) * 4;
    if (e0 >= E) return;
    int f32 = flags[0], i64 = flags[1];
    if (e0 + 4 <= E) {
        int4 r = *(const int4*)(rank + e0);
        int t0, t1, t2, t3, s0, s1, s2, s3;
        if (i64) {                                   // src at dword offset 2*e0: 16B-aligned
            const int4* q = (const int4*)(ei + 2 * (size_t)e0);
            int4 a = q[0], b = q[1];
            s0 = a.x; s1 = a.z; s2 = b.x; s3 = b.z;
        } else if (!(e0 & 3)) {
            int4 a = *(const int4*)(ei + e0);
            s0 = a.x; s1 = a.y; s2 = a.z; s3 = a.w;
        } else {
            s0 = ei[e0]; s1 = ei[e0 + 1]; s2 = ei[e0 + 2]; s3 = ei[e0 + 3];
        }
        if (i64 && !(E & 1)) {
            const int4* q = (const int4*)(ei + 2 * (size_t)(E + e0));
            int4 a = q[0], b = q[1];
            t0 = a.x; t1 = a.z; t2 = b.x; t3 = b.z;
        } else if (!i64 && !(E & 3)) {
            int4 a = *(const int4*)(ei + (size_t)E + e0);
            t0 = a.x; t1 = a.y; t2 = a.z; t3 = a.w;
        } else {
            t0 = eidx(ei, (size_t)E + e0 + 0, i64); t1 = eidx(ei, (size_t)E + e0 + 1, i64);
            t2 = eidx(ei, (size_t)E + e0 + 2, i64); t3 = eidx(ei, (size_t)E + e0 + 3, i64);
        }
        float w0 = ldw(ewf, ewh, e0 + 0, f32), w1 = ldw(ewf, ewh, e0 + 1, f32),
              w2 = ldw(ewf, ewh, e0 + 2, f32), w3 = ldw(ewf, ewh, e0 + 3, f32);
        int o0 = offsets[t0] + bpre[t0 >> 12] + r.x,
            o1 = offsets[t1] + bpre[t1 >> 12] + r.y,
            o2 = offsets[t2] + bpre[t2 >> 12] + r.z,
            o3 = offsets[t3] + bpre[t3 >> 12] + r.w;
        float a0 = expf(w0), a1 = expf(w1), a2 = expf(w2), a3 = expf(w3);
        if (PACK) {
            csr4[o0] = (unsigned)s0 | ((unsigned)__half_as_ushort(__float2half(a0)) << 16);
            csr4[o1] = (unsigned)s1 | ((unsigned)__half_as_ushort(__float2half(a1)) << 16);
            csr4[o2] = (unsigned)s2 | ((unsigned)__half_as_ushort(__float2half(a2)) << 16);
            csr4[o3] = (unsigned)s3 | ((unsigned)__half_as_ushort(__float2half(a3)) << 16);
        } else {
            csr8[o0] = make_uint2((unsigned)s0, __float_as_uint(a0));
            csr8[o1] = make_uint2((unsigned)s1, __float_as_uint(a1));
            csr8[o2] = make_uint2((unsigned)s2, __float_as_uint(a2));
            csr8[o3] = make_uint2((unsigned)s3, __float_as_uint(a3));
        }
    } else {
        for (int j = 0; j < 4 && e0 + j < E; ++j) {
            int e = e0 + j;
            int t = eidx(ei, (size_t)E + e, i64);
            int s = eidx(ei, e, i64);
            float al = expf(ldw(ewf, ewh, e, f32));
            int pos = offsets[t] + bpre[t >> 12] + rank[e];
            if (PACK) csr4[pos] = (unsigned)s | ((unsigned)__half_as_ushort(__float2half(al)) << 16);
            else      csr8[pos] = make_uint2((unsigned)s, __float_as_uint(al));
        }
    }
}

// ---------- CSR record decode ----------
template <int PACK>
__device__ __forceinline__ void dec_edge(const unsigned* __restrict__ c4,
                                         const uint2* __restrict__ c8, int j,
                                         unsigned& s, float& al) {
    if (PACK) {
        unsigned r = c4[j];
        s = r & 0xffffu;
        al = __half2float(__ushort_as_half((unsigned short)(r >> 16)));
    } else {
        uint2 e = c8[j];
        s = e.x;
        al = __uint_as_float(e.y);
    }
}

// ---------- K5: TWO nodes per wave (32 lanes each); always-8-deep predicated gather ----------
// Each lane covers 4 features (uint2 = 8B/edge, 256B/edge total, fully coalesced).
// aggb layout identical: node*64 u32 (written as node*32 uint2).
template <int PACK>
__global__ void aggregate(const unsigned* __restrict__ xb, const unsigned* __restrict__ xcvt,
                          const int* __restrict__ offsets, const int* __restrict__ bpre,
                          const unsigned* __restrict__ csr4, const uint2* __restrict__ csr8,
                          uint2* __restrict__ aggb2, const int* __restrict__ flags, int N) {
    int wid = blockIdx.x * 4 + (threadIdx.x >> 6);
    int half = (threadIdx.x >> 5) & 1;
    int node = wid * 2 + half;
    if (node >= N) return;
    int lane32 = threadIdx.x & 31;
    const uint2* xs2 = (const uint2*)(flags[0] ? xcvt : xb);  // bf16 rows, 32 uint2 each
    float a0 = 0.f, a1 = 0.f, a2 = 0.f, a3 = 0.f;
    int beg = offsets[node] + bpre[node >> 12];
    int end = offsets[node + 1] + bpre[(node + 1) >> 12];
    for (int j = beg; j < end; j += 8) {
        int last = end - 1;
        int j0 = j,     i0 = (j0 < end) ? j0 : last;
        int j1 = j + 1, i1 = (j1 < end) ? j1 : last;
        int j2 = j + 2, i2 = (j2 < end) ? j2 : last;
        int j3 = j + 3, i3 = (j3 < end) ? j3 : last;
        int j4 = j + 4, i4 = (j4 < end) ? j4 : last;
        int j5 = j + 5, i5 = (j5 < end) ? j5 : last;
        int j6 = j + 6, i6 = (j6 < end) ? j6 : last;
        int j7 = j + 7, i7 = (j7 < end) ? j7 : last;
        unsigned s0, s1, s2, s3, s4, s5, s6, s7;
        float l0, l1, l2, l3, l4, l5, l6, l7;
        dec_edge<PACK>(csr4, csr8, i0, s0, l0); dec_edge<PACK>(csr4, csr8, i1, s1, l1);
        dec_edge<PACK>(csr4, csr8, i2, s2, l2); dec_edge<PACK>(csr4, csr8, i3, s3, l3);
        dec_edge<PACK>(csr4, csr8, i4, s4, l4); dec_edge<PACK>(csr4, csr8, i5, s5, l5);
        dec_edge<PACK>(csr4, csr8, i6, s6, l6); dec_edge<PACK>(csr4, csr8, i7, s7, l7);
        uint2 p0 = xs2[s0 * 32 + lane32], p1 = xs2[s1 * 32 + lane32],
              p2 = xs2[s2 * 32 + lane32], p3 = xs2[s3 * 32 + lane32],
              p4 = xs2[s4 * 32 + lane32], p5 = xs2[s5 * 32 + lane32],
              p6 = xs2[s6 * 32 + lane32], p7 = xs2[s7 * 32 + lane32];
        l1 = (j1 < end) ? l1 : 0.f; l2 = (j2 < end) ? l2 : 0.f;
        l3 = (j3 < end) ? l3 : 0.f; l4 = (j4 < end) ? l4 : 0.f;
        l5 = (j5 < end) ? l5 : 0.f; l6 = (j6 < end) ? l6 : 0.f;
        l7 = (j7 < end) ? l7 : 0.f;
        a0 += l0 * lo16(p0.x); a1 += l0 * hi16(p0.x); a2 += l0 * lo16(p0.y); a3 += l0 * hi16(p0.y);
        a0 += l1 * lo16(p1.x); a1 += l1 * hi16(p1.x); a2 += l1 * lo16(p1.y); a3 += l1 * hi16(p1.y);
        a0 += l2 * lo16(p2.x); a1 += l2 * hi16(p2.x); a2 += l2 * lo16(p2.y); a3 += l2 * hi16(p2.y);
        a0 += l3 * lo16(p3.x); a1 += l3 * hi16(p3.x); a2 += l3 * lo16(p3.y); a3 += l3 * hi16(p3.y);
        a0 += l4 * lo16(p4.x); a1 += l4 * hi16(p4.x); a2 += l4 * lo16(p4.y); a3 += l4 * hi16(p4.y);
        a0 += l5 * lo16(p5.x); a1 += l5 * hi16(p5.x); a2 += l5 * lo16(p5.y); a3 += l5 * hi16(p5.y);
        a0 += l6 * lo16(p6.x); a1 += l6 * hi16(p6.x); a2 += l6 * lo16(p6.y); a3 += l6 * hi16(p6.y);
        a0 += l7 * lo16(p7.x); a1 += l7 * hi16(p7.x); a2 += l7 * lo16(p7.y); a3 += l7 * hi16(p7.y);
    }
    float ss = a0 * a0 + a1 * a1 + a2 * a2 + a3 * a3;
    #pragma unroll
    for (int m = 16; m >= 1; m >>= 1) ss += __shfl_xor(ss, m);   // reduce within 32-lane half
    float inv = 1.f / (sqrtf(ss) + EPS);
    aggb2[node * 32 + lane32] = make_uint2(f2b(a0 * inv) | (f2b(a1 * inv) << 16),
                                           f2b(a2 * inv) | (f2b(a3 * inv) << 16));
}

// ---------- K6: MFMA fused: C = 0.5*([x|agg] @ [Ws;Wn] + bs + bn) -> proj-norm -> LN ----------
// 64 nodes/block, 128 threads (2 waves), 32 KB LDS; each wave owns 32 nodes as TWO
// 16-row A-subtiles -> every loaded B fragment feeds 2 MFMAs (halves Wt L2 traffic/node).
// mfma_f32_16x16x32_bf16: C/D: col = lane&15, row = (lane>>4)*4 + reg  [learn_hip m89].
__global__ __launch_bounds__(128) void fused_mfma(
    const unsigned* __restrict__ xb, const unsigned* __restrict__ xcvt,
    const unsigned* __restrict__ aggb, const uint4* __restrict__ wt4,
    const float* __restrict__ bsf, const __hip_bfloat16* __restrict__ bsh,
    const float* __restrict__ bnf, const __hip_bfloat16* __restrict__ bnh,
    const float* __restrict__ gf, const __hip_bfloat16* __restrict__ gh,
    const float* __restrict__ tf, const __hip_bfloat16* __restrict__ th,
    float* __restrict__ outf, unsigned* __restrict__ outb,
    const int* __restrict__ flags, int N)
{
    __shared__ uint4 sA[2048];                   // 64 rows x 32 chunks of 16B = 32 KB
    int f32 = flags[0];
    const uint4* xs4 = (const uint4*)(f32 ? xcvt : xb);
    const uint4* ag4 = (const uint4*)aggb;
    int tid = threadIdx.x;
    int node0 = blockIdx.x * 64;

    // stage A: row r = [x bf16 (chunks 0-15) | agg bf16 (chunks 16-31)], XOR-swizzled
    #pragma unroll
    for (int i = 0; i < 16; ++i) {
        int ci = i * 128 + tid;
        int r = ci >> 5, c = ci & 31;
        int node = node0 + r;
        uint4 v = make_uint4(0, 0, 0, 0);
        if (node < N) v = (c < 16) ? xs4[node * 16 + c] : ag4[node * 16 + (c - 16)];
        sA[r * 32 + (c ^ (r & 15))] = v;
    }
    __syncthreads();

    int lane = tid & 63, w = tid >> 6, g = lane >> 4, c16 = lane & 15;
    int rloc0 = w * 32 + c16;                    // A row, subtile 0 (rloc0&15 == c16)
    int rloc1 = rloc0 + 16;                      // A row, subtile 1 (rloc1&15 == c16)

    f32x4 acc0[8], acc1[8];
    #pragma unroll
    for (int t = 0; t < 8; ++t) {
        acc0[t] = (f32x4){0.f, 0.f, 0.f, 0.f};
        acc1[t] = (f32x4){0.f, 0.f, 0.f, 0.f};
    }

    #pragma unroll
    for (int kk = 0; kk < 8; ++kk) {             // K = 256 in steps of 32
        int cs = (kk * 4 + g) ^ c16;
        bf16x8 a0 = __builtin_bit_cast(bf16x8, sA[rloc0 * 32 + cs]);
        bf16x8 a1 = __builtin_bit_cast(bf16x8, sA[rloc1 * 32 + cs]);
        #pragma unroll
        for (int t = 0; t < 8; ++t) {            // 8 feature tiles of 16; B reused 2x
            uint4 bv = wt4[(t * 16 + c16) * 32 + kk * 4 + g];
            bf16x8 b = __builtin_bit_cast(bf16x8, bv);
            acc0[t] = __builtin_amdgcn_mfma_f32_16x16x32_bf16(a0, b, acc0[t], 0, 0, 0);
            acc1[t] = __builtin_amdgcn_mfma_f32_16x16x32_bf16(a1, b, acc1[t], 0, 0, 0);
        }
    }

    // per-lane feature params (features f = t*16 + c16)
    float bsum[8], gam[8], bet[8];
    #pragma unroll
    for (int t = 0; t < 8; ++t) {
        int f = t * 16 + c16;
        bsum[t] = ldw(bsf, bsh, f, f32) + ldw(bnf, bnh, f, f32);
        gam[t]  = ldw(gf, gh, f, f32);
        bet[t]  = ldw(tf, th, f, f32);
    }

    // epilogue: per node (4 per lane per subtile), reduce over 16-lane group
    auto epilogue = [&](f32x4* acc, int rowbase) {
        #pragma unroll
        for (int reg = 0; reg < 4; ++reg) {
            int node = node0 + rowbase + g * 4 + reg;
            float cv[8], s1 = 0.f, s2 = 0.f;
            #pragma unroll
            for (int t = 0; t < 8; ++t) {
                float c_ = 0.5f * (acc[t][reg] + bsum[t]);
                cv[t] = c_; s1 += c_; s2 += c_ * c_;
            }
            #pragma unroll
            for (int m = 1; m < 16; m <<= 1) { s1 += __shfl_xor(s1, m); s2 += __shfl_xor(s2, m); }
            float inv  = 1.f / (sqrtf(s2) + EPS);
            float mean = s1 * inv * (1.f / 128.f);
            float var  = s2 * inv * inv * (1.f / 128.f) - mean * mean;
            float rstd = 1.f / sqrtf(var + LN_EPS);
            if (f32) {
                if (node < N) {
                    #pragma unroll
                    for (int t = 0; t < 8; ++t) {
                        float o = (cv[t] * inv - mean) * rstd * gam[t] + bet[t];
                        outf[(size_t)node * 128 + t * 16 + c16] = o;
                    }
                }
            } else {
                #pragma unroll
                for (int t = 0; t < 8; ++t) {
                    float o = (cv[t] * inv - mean) * rstd * gam[t] + bet[t];
                    float po = __shfl_xor(o, 1);
                    if (!(c16 & 1) && node < N)
                        outb[node * 64 + t * 8 + (c16 >> 1)] = f2b(o) | (f2b(po) << 16);
                }
            }
        }
    };
    epilogue(acc0, w * 32);
    epilogue(acc1, w * 32 + 16);
}

static inline size_t rup16(size_t x) { return (x + 15) & ~(size_t)15; }

extern "C" void kernel_launch(void* const* d_in, const int* in_sizes, int n_in,
                              void* d_out, int out_size, void* d_ws, size_t ws_size,
                              hipStream_t stream) {
    int N = in_sizes[0] / 128;
    int E = in_sizes[1] / 2;
    const int* ei = (const int*)d_in[1];

    char* p = (char*)d_ws;
    int* flags = (int*)p;              p += 16;
    int* ticket = (int*)p;             p += 16;
    int* count = (int*)p;              p += rup16((size_t)N * 4);
    int* offsets = (int*)p;            p += rup16((size_t)(N + 4) * 4);
    int* bsum = (int*)p;               p += 256;                       // up to 64 block sums
    int* bpre = (int*)p;               p += 512;                       // block-prefix table [B+1]
    int* rank = (int*)p;               p += rup16((size_t)E * 4);
    unsigned* csr4 = (unsigned*)p;                                     // aliases csr8 region
    uint2* csr8 = (uint2*)p;           p += rup16((size_t)E * 8);
    unsigned* wt = (unsigned*)p;       p += 128 * 128 * 4;             // 64 KB bf16 Wt[128][256]
    unsigned* xcvt = (unsigned*)p;     p += rup16((size_t)N * 64 * 4); // 12.8 MB bf16 x copy
    unsigned* aggb = (unsigned*)p;     // N*64 u32 = 12.8 MB bf16 agg

    int eb4 = (E + 1023) / 1024;
    int nb2 = (N + 7) / 8;                       // aggregate: 8 nodes/block (2 per wave)
    int nbf = (N + 63) / 64;                     // fused_mfma: 64 nodes/block
    int ncv = (N * 32 + 255) / 256;
    int scanB = (N + 4095) / 4096;
    int N4z = (int)(rup16((size_t)N * 4) / 16);                        // uint4s to zero in count
    int zb = (N4z + 255) / 256;
    int pack = (N <= 65536);

    prep<<<64 + zb + ncv, 256, 0, stream>>>((const unsigned*)d_in[0], (const float4*)d_in[0],
                                            (uint2*)xcvt, ei,
                                            (const unsigned*)d_in[3], (const float*)d_in[3],
                                            (const unsigned*)d_in[5], (const float*)d_in[5],
                                            wt, (int4*)count, flags, ticket, N * 32, zb, N4z);
    edge_count<<<eb4, 256, 0, stream>>>(ei, count, rank, flags, E);
    scan_blocks<<<scanB, 1024, 0, stream>>>(count, offsets, bsum, bpre, ticket, N, scanB);
    if (pack)
        edge_scatter<1><<<eb4, 256, 0, stream>>>(ei, rank, (const float*)d_in[2],
                                                 (const __hip_bfloat16*)d_in[2],
                                                 offsets, bpre, csr4, csr8, flags, E);
    else
        edge_scatter<0><<<eb4, 256, 0, stream>>>(ei, rank, (const float*)d_in[2],
                                                 (const __hip_bfloat16*)d_in[2],
                                                 offsets, bpre, csr4, csr8, flags, E);
    if (pack)
        aggregate<1><<<nb2, 256, 0, stream>>>((const unsigned*)d_in[0], xcvt,
                                              offsets, bpre, csr4, csr8, (uint2*)aggb, flags, N);
    else
        aggregate<0><<<nb2, 256, 0, stream>>>((const unsigned*)d_in[0], xcvt,
                                              offsets, bpre, csr4, csr8, (uint2*)aggb, flags, N);
    fused_mfma<<<nbf, 128, 0, stream>>>((const unsigned*)d_in[0], xcvt, aggb, (const uint4*)wt,
                                        (const float*)d_in[4], (const __hip_bfloat16*)d_in[4],
                                        (const float*)d_in[6], (const __hip_bfloat16*)d_in[6],
                                        (const float*)d_in[7], (const __hip_bfloat16*)d_in[7],
                                        (const float*)d_in[8], (const __hip_bfloat16*)d_in[8],
                                        (float*)d_out, (unsigned*)d_out, flags, N);
}